// Round 1
// baseline (355.718 us; speedup 1.0000x reference)
//
#include <hip/hip_runtime.h>
#include <math.h>

#define CLAMPV 1000000.0f
#define NLEAF 1024
#define NSUB 4           // subtrees per element
#define SUBLEAF 256      // leaves per subtree
#define ELEM_PER_BLK 64

// sanitize: nan -> 0, then clamp to [-1e6, 1e6] (inf absorbed by fmin/fmax)
__device__ __forceinline__ float sanit(float v) {
    if (isnan(v)) return 0.0f;
    return fminf(CLAMPV, fmaxf(-CLAMPV, v));
}

// One tree-node combine, replicating numpy complex64 semantics:
//   u = (g0 + g1*x) + g2*left ; v = (g3 + g4*x) + g5*right   (g, x real -> complex with +0 imag)
//   out = sanitize(exp(log(u) * log(v)))
// Signed-zero products are kept literal so atan2(+-0, negative) matches numpy.
__device__ __forceinline__ void node_combine(
    float lre, float lim, float rre, float rim,
    float x, const float* __restrict__ g,
    float& ore, float& oim)
{
    float g0 = g[0], g1 = g[1], g2 = g[2];
    float g3 = g[3], g4 = g[4], g5 = g[5];

    float ure = (g0 + (g1 * x - 0.0f * 0.0f)) + (g2 * lre - 0.0f * lim);
    float uim = (0.0f + (g1 * 0.0f + 0.0f * x)) + (g2 * lim + 0.0f * lre);
    float vre = (g3 + (g4 * x - 0.0f * 0.0f)) + (g5 * rre - 0.0f * rim);
    float vim = (0.0f + (g4 * 0.0f + 0.0f * x)) + (g5 * rim + 0.0f * rre);

    // complex log: (0.5*log(re^2+im^2), atan2(im, re))
    float lure = 0.5f * logf(ure * ure + uim * uim);
    float luim = atan2f(uim, ure);
    float lvre = 0.5f * logf(vre * vre + vim * vim);
    float lvim = atan2f(vim, vre);

    // w = log(u) * log(v)
    float wre = lure * lvre - luim * lvim;
    float wim = lure * lvim + luim * lvre;

    // exp(w) = exp(wre) * (cos(wim) + i sin(wim))
    float r = expf(wre);
    float sn, cs;
    sincosf(wim, &sn, &cs);

    ore = sanit(r * cs);
    oim = sanit(r * sn);
}

// Block: 64 elements (threadIdx.x = lane/element) x 4 subtrees (threadIdx.y).
// Each thread DFS-reduces its 256-leaf subtree (levels 0..7); levels 8,9 via LDS tail.
__global__ __launch_bounds__(256, 4) void EMLTree1DLinear_kernel(
    const float* __restrict__ x_g,      // [batch]
    const float* __restrict__ leaf_g,   // [1024][2]
    const float* __restrict__ gate_g,   // [1023][2][3] flat
    float* __restrict__ out,            // [batch][2] interleaved complex (or [batch] real if out_real_only)
    int batch, int out_real_only)
{
    __shared__ float s_gate[1023 * 6];                 // 24552 B
    __shared__ float s_stkre[6][256];                  // stack levels 2..7, 6144 B
    __shared__ float s_stkim[6][256];                  // 6144 B
    __shared__ float s_tre[6][ELEM_PER_BLK];           // tail: rows 0..3 = level-8 vals, 4..5 = level-9 vals
    __shared__ float s_tim[6][ELEM_PER_BLK];           // 3072 B total tail

    const int lane = threadIdx.x;          // element within block, 0..63
    const int s    = threadIdx.y;          // subtree, 0..3
    const int tid  = lane + 64 * s;        // 0..255

    for (int i = tid; i < 1023 * 6; i += 256) s_gate[i] = gate_g[i];
    __syncthreads();

    const int e = blockIdx.x * ELEM_PER_BLK + lane;
    const float x = x_g[e];

    float cre = 0.0f, cim = 0.0f;
    const int j0 = s * SUBLEAF;

    // 64 groups of 4 leaves; levels 0 and 1 handled statically, level>=2 via LDS stack
    for (int q = 0; q < SUBLEAF / 4; ++q) {
        const int j = j0 + 4 * q;

        // leaves: level = a + b * x (complex; imag term kept literal -> always +0)
        float a0 = leaf_g[2 * j + 0], b0 = leaf_g[2 * j + 1];
        float a1 = leaf_g[2 * j + 2], b1 = leaf_g[2 * j + 3];
        float a2 = leaf_g[2 * j + 4], b2 = leaf_g[2 * j + 5];
        float a3 = leaf_g[2 * j + 6], b3 = leaf_g[2 * j + 7];

        float v0re = a0 + (b0 * x - 0.0f * 0.0f), v0im = 0.0f + (b0 * 0.0f + 0.0f * x);
        float v1re = a1 + (b1 * x - 0.0f * 0.0f), v1im = 0.0f + (b1 * 0.0f + 0.0f * x);
        float v2re = a2 + (b2 * x - 0.0f * 0.0f), v2im = 0.0f + (b2 * 0.0f + 0.0f * x);
        float v3re = a3 + (b3 * x - 0.0f * 0.0f), v3im = 0.0f + (b3 * 0.0f + 0.0f * x);

        // level 0: nodes (j>>1), (j>>1)+1   (base[0] = 0)
        float Are, Aim, Bre, Bim;
        node_combine(v0re, v0im, v1re, v1im, x, &s_gate[(j >> 1) * 6], Are, Aim);
        node_combine(v2re, v2im, v3re, v3im, x, &s_gate[((j >> 1) + 1) * 6], Bre, Bim);

        // level 1: node base[1]=512 + (j>>2)
        node_combine(Are, Aim, Bre, Bim, x, &s_gate[(512 + (j >> 2)) * 6], cre, cim);

        // push/merge at level >= 2
        int idx = j >> 2;            // position at level 2
        int L = 2;
        while ((idx & 1) && (L < 8)) {
            const int pair = idx >> 1;
            const int node = (NLEAF - (NLEAF >> L)) + pair;   // base[L] + pair
            node_combine(s_stkre[L - 2][tid], s_stkim[L - 2][tid], cre, cim,
                         x, &s_gate[node * 6], cre, cim);
            idx = pair;
            ++L;
        }
        if (L < 8) { s_stkre[L - 2][tid] = cre; s_stkim[L - 2][tid] = cim; }
        // (last group: L reaches 8, cre/cim hold the subtree value)
    }

    // cre/cim = value at level-8 position s for element e
    s_tre[s][lane] = cre; s_tim[s][lane] = cim;
    __syncthreads();

    // level 8: nodes 1020, 1021 (positions (0,1) and (2,3))
    if (s < 2) {
        float r1, i1;
        node_combine(s_tre[2 * s][lane], s_tim[2 * s][lane],
                     s_tre[2 * s + 1][lane], s_tim[2 * s + 1][lane],
                     x, &s_gate[(1020 + s) * 6], r1, i1);
        s_tre[4 + s][lane] = r1; s_tim[4 + s][lane] = i1;
    }
    __syncthreads();

    // level 9: node 1022 -> final output
    if (s == 0) {
        float r2, i2;
        node_combine(s_tre[4][lane], s_tim[4][lane],
                     s_tre[5][lane], s_tim[5][lane],
                     x, &s_gate[1022 * 6], r2, i2);
        if (out_real_only) {
            out[e] = r2;
        } else {
            reinterpret_cast<float2*>(out)[e] = make_float2(r2, i2);
        }
    }
}

extern "C" void kernel_launch(void* const* d_in, const int* in_sizes, int n_in,
                              void* d_out, int out_size, void* d_ws, size_t ws_size,
                              hipStream_t stream) {
    const float* x    = (const float*)d_in[0];
    const float* leaf = (const float*)d_in[1];
    const float* gate = (const float*)d_in[2];
    float* out = (float*)d_out;
    const int batch = in_sizes[0];

    // complex64 output is normally viewed as interleaved float pairs (out_size == 2*batch);
    // fall back to real-only if the harness sized d_out as one float per element.
    const int out_real_only = (out_size == batch) ? 1 : 0;

    dim3 block(64, NSUB);
    dim3 grid(batch / ELEM_PER_BLK);
    hipLaunchKernelGGL(EMLTree1DLinear_kernel, grid, block, 0, stream,
                       x, leaf, gate, out, batch, out_real_only);
}

// Round 2
// 165.527 us; speedup vs baseline: 2.1490x; 2.1490x over previous
//
#include <hip/hip_runtime.h>
#include <math.h>

#define CLAMPV 1000000.0f
#define NLEAF 1024
#define NSUB 4           // subtrees per element
#define SUBLEAF 256      // leaves per subtree
#define ELEM_PER_BLK 64

#define PI_F     3.14159274f
#define HALFPI_F 1.57079633f
#define HALF_LN2 0.34657359f      // 0.5 * ln(2)
#define LN2_F    0.69314718f
#define L2E_F    1.44269504f      // 1/ln(2)
#define INV2PI_F 0.15915494f      // 1/(2*pi)

// sanitize: nan -> 0, then clamp to [-1e6, 1e6] (inf absorbed by fmin/fmax)
__device__ __forceinline__ float sanit(float v) {
    float c = fminf(CLAMPV, fmaxf(-CLAMPV, v));
    return (v != v) ? 0.0f : c;
}

// fast atan2: rcp + deg-11 minimax poly + quadrant fixup.
// (+0, x>0) -> +0 ; (+0, x<0) -> +pi  (matches numpy atan2 for the
// exact-zero-imag chains, where numpy's sum structure forces imag = +0).
__device__ __forceinline__ float fatan2(float y, float x) {
    float ax = __builtin_fabsf(x), ay = __builtin_fabsf(y);
    float mx = fmaxf(ax, ay), mn = fminf(ax, ay);
    float t = mn * __builtin_amdgcn_rcpf(mx);
    float z = t * t;
    float p = fmaf(z, fmaf(z, fmaf(z, fmaf(z, fmaf(z,
              -0.0117212f, 0.05265332f), -0.11643287f), 0.19354346f),
              -0.33262347f), 0.99997726f);
    p = p * t;
    p = (ay > ax) ? (HALFPI_F - p) : p;
    p = (x < 0.0f) ? (PI_F - p) : p;
    return copysignf(p, y);
}

// exp(w) tail: out = sanitize(exp(wre) * (cos(wim) + i sin(wim)))
__device__ __forceinline__ void exp_tail(float wre, float wim, float& ore, float& oim) {
    float r  = __builtin_amdgcn_exp2f(wre * L2E_F);
    float f  = __builtin_amdgcn_fractf(wim * INV2PI_F);   // revolutions in [0,1)
    float sn = __builtin_amdgcn_sinf(f);
    float cs = __builtin_amdgcn_cosf(f);
    ore = sanit(r * cs);
    oim = sanit(r * sn);
}

// General node combine (complex children):
//   u = g0 + g1*x + g2*l ; v = g3 + g4*x + g5*r ; out = sanitize(exp(log u * log v))
// The "+ 0.0f" on the imag parts is load-bearing: it forces -0 -> +0 so the
// atan2 branch choice matches numpy when a child's imag is exactly zero.
__device__ __forceinline__ void node_c(
    float lre, float lim, float rre, float rim,
    float x, const float* __restrict__ g,
    float& ore, float& oim)
{
    float ure = fmaf(g[2], lre, fmaf(g[1], x, g[0]));
    float uim = g[2] * lim + 0.0f;
    float vre = fmaf(g[5], rre, fmaf(g[4], x, g[3]));
    float vim = g[5] * rim + 0.0f;

    float nu = fmaf(ure, ure, uim * uim);
    float nv = fmaf(vre, vre, vim * vim);
    float lure = HALF_LN2 * __builtin_amdgcn_logf(nu);
    float lvre = HALF_LN2 * __builtin_amdgcn_logf(nv);
    float luim = fatan2(uim, ure);
    float lvim = fatan2(vim, vre);

    float wre = fmaf(lure, lvre, -(luim * lvim));
    float wim = fmaf(lure, lvim, luim * lvre);
    exp_tail(wre, wim, ore, oim);
}

// Level-0 node with real scalar children (leaf values): no atan2 needed.
// numpy: imag is exactly +0 here, so log(u) = (ln|u|, u<0 ? +pi : 0).
__device__ __forceinline__ void node_r(
    float l, float r, float x, const float* __restrict__ g,
    float& ore, float& oim)
{
    float u = fmaf(g[2], l, fmaf(g[1], x, g[0]));
    float v = fmaf(g[5], r, fmaf(g[4], x, g[3]));
    float lure = LN2_F * __builtin_amdgcn_logf(__builtin_fabsf(u));
    float lvre = LN2_F * __builtin_amdgcn_logf(__builtin_fabsf(v));
    float luim = (u < 0.0f) ? PI_F : 0.0f;
    float lvim = (v < 0.0f) ? PI_F : 0.0f;

    float wre = fmaf(lure, lvre, -(luim * lvim));
    float wim = fmaf(lure, lvim, luim * lvre);
    exp_tail(wre, wim, ore, oim);
}

// Block: 64 elements (threadIdx.x = lane/element) x 4 subtrees (threadIdx.y).
// Each thread DFS-reduces its 256-leaf subtree (levels 0..7); levels 8,9 via LDS tail.
__global__ __launch_bounds__(256, 4) void EMLTree1DLinear_kernel(
    const float* __restrict__ x_g,      // [batch]
    const float* __restrict__ leaf_g,   // [1024][2]
    const float* __restrict__ gate_g,   // [1023][2][3] flat
    float* __restrict__ out,            // [batch][2] interleaved complex (or [batch] real)
    int batch, int out_real_only)
{
    __shared__ float s_gate[1023 * 6];                 // 24552 B
    __shared__ float s_stkre[6][256];                  // stack levels 2..7
    __shared__ float s_stkim[6][256];
    __shared__ float s_tre[6][ELEM_PER_BLK];           // tail: 0..3 level-8, 4..5 level-9
    __shared__ float s_tim[6][ELEM_PER_BLK];

    const int lane = threadIdx.x;          // element within block, 0..63
    const int s    = threadIdx.y;          // subtree, 0..3
    const int tid  = lane + 64 * s;        // 0..255

    for (int i = tid; i < 1023 * 6; i += 256) s_gate[i] = gate_g[i];
    __syncthreads();

    const int e = blockIdx.x * ELEM_PER_BLK + lane;
    const float x = x_g[e];

    float cre = 0.0f, cim = 0.0f;
    const int j0 = s * SUBLEAF;

    // 64 groups of 4 leaves; levels 0 and 1 static, level>=2 via LDS stack.
    for (int q = 0; q < SUBLEAF / 4; ++q) {
        const int j = j0 + 4 * q;

        // leaves (real): v_k = a_k + b_k * x
        float v0 = fmaf(leaf_g[2 * j + 1], x, leaf_g[2 * j + 0]);
        float v1 = fmaf(leaf_g[2 * j + 3], x, leaf_g[2 * j + 2]);
        float v2 = fmaf(leaf_g[2 * j + 5], x, leaf_g[2 * j + 4]);
        float v3 = fmaf(leaf_g[2 * j + 7], x, leaf_g[2 * j + 6]);

        // level 0 (real children): nodes (j>>1), (j>>1)+1
        float Are, Aim, Bre, Bim;
        node_r(v0, v1, x, &s_gate[(j >> 1) * 6], Are, Aim);
        node_r(v2, v3, x, &s_gate[((j >> 1) + 1) * 6], Bre, Bim);

        // level 1: node 512 + (j>>2)
        node_c(Are, Aim, Bre, Bim, x, &s_gate[(512 + (j >> 2)) * 6], cre, cim);

        // push/merge at level >= 2 (trip count is wave-uniform: j0 = s*256)
        int idx = j >> 2;            // position at level 2
        int L = 2;
        while ((idx & 1) && (L < 8)) {
            const int pair = idx >> 1;
            const int node = (NLEAF - (NLEAF >> L)) + pair;   // base[L] + pair
            node_c(s_stkre[L - 2][tid], s_stkim[L - 2][tid], cre, cim,
                   x, &s_gate[node * 6], cre, cim);
            idx = pair;
            ++L;
        }
        if (L < 8) { s_stkre[L - 2][tid] = cre; s_stkim[L - 2][tid] = cim; }
    }

    // cre/cim = value at level-8 position s for element e
    s_tre[s][lane] = cre; s_tim[s][lane] = cim;
    __syncthreads();

    // level 8: nodes 1020, 1021
    if (s < 2) {
        float r1, i1;
        node_c(s_tre[2 * s][lane], s_tim[2 * s][lane],
               s_tre[2 * s + 1][lane], s_tim[2 * s + 1][lane],
               x, &s_gate[(1020 + s) * 6], r1, i1);
        s_tre[4 + s][lane] = r1; s_tim[4 + s][lane] = i1;
    }
    __syncthreads();

    // level 9: node 1022 -> final output
    if (s == 0) {
        float r2, i2;
        node_c(s_tre[4][lane], s_tim[4][lane],
               s_tre[5][lane], s_tim[5][lane],
               x, &s_gate[1022 * 6], r2, i2);
        if (out_real_only) {
            out[e] = r2;
        } else {
            reinterpret_cast<float2*>(out)[e] = make_float2(r2, i2);
        }
    }
}

extern "C" void kernel_launch(void* const* d_in, const int* in_sizes, int n_in,
                              void* d_out, int out_size, void* d_ws, size_t ws_size,
                              hipStream_t stream) {
    const float* x    = (const float*)d_in[0];
    const float* leaf = (const float*)d_in[1];
    const float* gate = (const float*)d_in[2];
    float* out = (float*)d_out;
    const int batch = in_sizes[0];

    const int out_real_only = (out_size == batch) ? 1 : 0;

    dim3 block(64, NSUB);
    dim3 grid(batch / ELEM_PER_BLK);
    hipLaunchKernelGGL(EMLTree1DLinear_kernel, grid, block, 0, stream,
                       x, leaf, gate, out, batch, out_real_only);
}

// Round 3
// 141.911 us; speedup vs baseline: 2.5066x; 1.1664x over previous
//
#include <hip/hip_runtime.h>
#include <math.h>

#define CLAMPV 1000000.0f
#define PI_F     3.14159274f
#define HALFPI_F 1.57079633f
#define HALF_LN2 0.34657359f      // 0.5 * ln(2)
#define LN2_F    0.69314718f
#define L2E_F    1.44269504f      // 1/ln(2)
#define INV2PI_F 0.15915494f      // 1/(2*pi)

typedef float v2f __attribute__((ext_vector_type(2)));

__device__ __forceinline__ v2f vb(float s) { return (v2f){s, s}; }
__device__ __forceinline__ v2f vfma(v2f a, v2f b, v2f c) { return __builtin_elementwise_fma(a, b, c); }

// sanitize: nan -> 0, clamp to [-1e6,1e6] (med3 absorbs +-inf)
__device__ __forceinline__ v2f sanitv(v2f v) {
    v2f c;
    c.x = __builtin_amdgcn_fmed3f(v.x, -CLAMPV, CLAMPV);
    c.y = __builtin_amdgcn_fmed3f(v.y, -CLAMPV, CLAMPV);
    c.x = (v.x != v.x) ? 0.0f : c.x;
    c.y = (v.y != v.y) ? 0.0f : c.y;
    return c;
}

// packed fast atan2 (deg-11 minimax); (+0, x<0) -> +pi matches numpy for the
// exact-zero-imag chains (imag forced to +0 upstream).
__device__ __forceinline__ v2f fatan2v(v2f y, v2f x) {
    v2f ax = __builtin_elementwise_abs(x);
    v2f ay = __builtin_elementwise_abs(y);
    v2f mx = __builtin_elementwise_max(ax, ay);
    v2f mn = __builtin_elementwise_min(ax, ay);
    v2f r  = (v2f){__builtin_amdgcn_rcpf(mx.x), __builtin_amdgcn_rcpf(mx.y)};
    v2f t  = mn * r;
    v2f z  = t * t;
    v2f p  = vfma(z, vfma(z, vfma(z, vfma(z, vfma(z,
             vb(-0.0117212f), vb(0.05265332f)), vb(-0.11643287f)), vb(0.19354346f)),
             vb(-0.33262347f)), vb(0.99997726f));
    p = p * t;
    p.x = (ay.x > ax.x) ? (HALFPI_F - p.x) : p.x;
    p.y = (ay.y > ax.y) ? (HALFPI_F - p.y) : p.y;
    p.x = (x.x < 0.0f) ? (PI_F - p.x) : p.x;
    p.y = (x.y < 0.0f) ? (PI_F - p.y) : p.y;
    p.x = copysignf(p.x, y.x);
    p.y = copysignf(p.y, y.y);
    return p;
}

// exp(w) tail: out = sanitize(exp(wre) * (cos(wim) + i sin(wim)))
__device__ __forceinline__ void exp_tailv(v2f wre, v2f wim, v2f& ore, v2f& oim) {
    v2f e = wre * vb(L2E_F);
    v2f r = (v2f){__builtin_amdgcn_exp2f(e.x), __builtin_amdgcn_exp2f(e.y)};
    v2f f0 = wim * vb(INV2PI_F);
    v2f f = (v2f){__builtin_amdgcn_fractf(f0.x), __builtin_amdgcn_fractf(f0.y)};
    v2f sn = (v2f){__builtin_amdgcn_sinf(f.x), __builtin_amdgcn_sinf(f.y)};
    v2f cs = (v2f){__builtin_amdgcn_cosf(f.x), __builtin_amdgcn_cosf(f.y)};
    ore = sanitv(r * cs);
    oim = sanitv(r * sn);
}

// General node combine (complex children), 2 elements packed.
// fma(g2, lim, +0) forces -0 -> +0 on the imag parts (load-bearing for the
// atan2 branch choice when a child's imag is exactly zero).
__device__ __forceinline__ void node_cv(
    v2f lre, v2f lim, v2f rre, v2f rim,
    v2f x, const float* __restrict__ g,
    v2f& ore, v2f& oim)
{
    v2f ure = vfma(vb(g[2]), lre, vfma(vb(g[1]), x, vb(g[0])));
    v2f uim = vfma(vb(g[2]), lim, vb(0.0f));
    v2f vre = vfma(vb(g[5]), rre, vfma(vb(g[4]), x, vb(g[3])));
    v2f vim = vfma(vb(g[5]), rim, vb(0.0f));

    v2f nu = vfma(ure, ure, uim * uim);
    v2f nv = vfma(vre, vre, vim * vim);
    v2f lure = vb(HALF_LN2) * (v2f){__builtin_amdgcn_logf(nu.x), __builtin_amdgcn_logf(nu.y)};
    v2f lvre = vb(HALF_LN2) * (v2f){__builtin_amdgcn_logf(nv.x), __builtin_amdgcn_logf(nv.y)};
    v2f luim = fatan2v(uim, ure);
    v2f lvim = fatan2v(vim, vre);

    v2f wre = vfma(lure, lvre, -(luim * lvim));
    v2f wim = vfma(lure, lvim, luim * lvre);
    exp_tailv(wre, wim, ore, oim);
}

// Round-0 node with real children (leaf values): no atan2 needed.
__device__ __forceinline__ void node_rv(
    v2f l, v2f r, v2f x, const float* __restrict__ g,
    v2f& ore, v2f& oim)
{
    v2f u = vfma(vb(g[2]), l, vfma(vb(g[1]), x, vb(g[0])));
    v2f v = vfma(vb(g[5]), r, vfma(vb(g[4]), x, vb(g[3])));
    v2f au = __builtin_elementwise_abs(u);
    v2f av = __builtin_elementwise_abs(v);
    v2f lure = vb(LN2_F) * (v2f){__builtin_amdgcn_logf(au.x), __builtin_amdgcn_logf(au.y)};
    v2f lvre = vb(LN2_F) * (v2f){__builtin_amdgcn_logf(av.x), __builtin_amdgcn_logf(av.y)};
    v2f luim, lvim;
    luim.x = (u.x < 0.0f) ? PI_F : 0.0f;
    luim.y = (u.y < 0.0f) ? PI_F : 0.0f;
    lvim.x = (v.x < 0.0f) ? PI_F : 0.0f;
    lvim.y = (v.y < 0.0f) ? PI_F : 0.0f;

    v2f wre = vfma(lure, lvre, -(luim * lvim));
    v2f wim = vfma(lure, lvim, luim * lvre);
    exp_tailv(wre, wim, ore, oim);
}

// Block: 64 lanes x 8 subtrees (512 threads). Each lane owns 2 batch elements
// (e0 = blk*128 + lane, e1 = e0 + 64), all math 2-wide packed (v_pk_fma_f32).
// Each thread reduces a 128-leaf subtree: rounds 0-3 in registers (16-leaf
// static groups), rounds 4-6 via 3-level LDS stack, rounds 7-9 in LDS tail.
__global__ __launch_bounds__(512, 4) void EMLTree1DLinear_kernel(
    const float* __restrict__ x_g,      // [batch]
    const float* __restrict__ leaf_g,   // [1024][2]
    const float* __restrict__ gate_g,   // [1023][2][3] flat
    float* __restrict__ out,            // [batch][2] interleaved complex (or [batch] real)
    int batch, int out_real_only)
{
    __shared__ float  s_gate[1023 * 6];   // 24552 B
    __shared__ float4 s_stk[3][512];      // 24576 B  (re0,re1,im0,im1) per thread, rounds 3..5 pushes
    __shared__ float4 s_t[14][64];        // 14336 B  tail: rows 0..7 round-6, 8..11 round-7, 12..13 round-8

    const int lane = threadIdx.x;         // 0..63
    const int s    = threadIdx.y;         // subtree, 0..7
    const int tid  = lane + 64 * s;       // 0..511

    for (int i = tid; i < 1023 * 6; i += 512) s_gate[i] = gate_g[i];
    __syncthreads();

    const int e0 = blockIdx.x * 128 + lane;
    const v2f x2 = (v2f){x_g[e0], x_g[e0 + 64]};

    const float4* lf4 = reinterpret_cast<const float4*>(leaf_g);

    v2f cre = vb(0.0f), cim = vb(0.0f);

    // 8 groups of 16 leaves
    for (int q = 0; q < 8; ++q) {
        const int jq = 128 * s + 16 * q;   // leftmost leaf of this group
        v2f r2re[2], r2im[2];
        v2f h1re = vb(0.0f), h1im = vb(0.0f);

#pragma unroll
        for (int p = 0; p < 4; ++p) {
            const int j = jq + 4 * p;
            // 4 leaves (addresses wave-uniform): a0,b0,a1,b1 | a2,b2,a3,b3
            float4 La = lf4[(j >> 1) + 0];
            float4 Lb = lf4[(j >> 1) + 1];
            v2f l0 = vfma(vb(La.y), x2, vb(La.x));
            v2f l1 = vfma(vb(La.w), x2, vb(La.z));
            v2f l2 = vfma(vb(Lb.y), x2, vb(Lb.x));
            v2f l3 = vfma(vb(Lb.w), x2, vb(Lb.z));

            // round 0: nodes (j>>1), (j>>1)+1
            v2f Are, Aim, Bre, Bim;
            node_rv(l0, l1, x2, &s_gate[6 * ((j >> 1))], Are, Aim);
            node_rv(l2, l3, x2, &s_gate[6 * ((j >> 1) + 1)], Bre, Bim);

            // round 1: node 512 + (j>>2)
            v2f r1re, r1im;
            node_cv(Are, Aim, Bre, Bim, x2, &s_gate[6 * (512 + (j >> 2))], r1re, r1im);

            if (p & 1) {
                // round 2: node 768 + (j>>3)
                node_cv(h1re, h1im, r1re, r1im, x2,
                        &s_gate[6 * (768 + (j >> 3))], r2re[p >> 1], r2im[p >> 1]);
            } else {
                h1re = r1re; h1im = r1im;
            }
        }
        // round 3: node 896 + (jq>>4)
        node_cv(r2re[0], r2im[0], r2re[1], r2im[1], x2,
                &s_gate[6 * (896 + (jq >> 4))], cre, cim);

        // rounds 4..6 via LDS stack (wave-uniform trip count)
        int idx = 8 * s + q;     // position at round 3
        int Rc = 3;
        while ((idx & 1) && (Rc < 6)) {
            const int node = (1024 - (1024 >> (Rc + 1))) + (idx >> 1);
            float4 st = s_stk[Rc - 3][tid];
            node_cv((v2f){st.x, st.y}, (v2f){st.z, st.w}, cre, cim,
                    x2, &s_gate[6 * node], cre, cim);
            idx >>= 1;
            ++Rc;
        }
        if (Rc < 6) s_stk[Rc - 3][tid] = make_float4(cre.x, cre.y, cim.x, cim.y);
    }

    // round-6 value (128-leaf subtree root) -> tail
    s_t[s][lane] = make_float4(cre.x, cre.y, cim.x, cim.y);
    __syncthreads();

    // round 7: nodes 1016..1019
    if (s < 4) {
        float4 a = s_t[2 * s][lane], b = s_t[2 * s + 1][lane];
        v2f r7re, r7im;
        node_cv((v2f){a.x, a.y}, (v2f){a.z, a.w}, (v2f){b.x, b.y}, (v2f){b.z, b.w},
                x2, &s_gate[6 * (1016 + s)], r7re, r7im);
        s_t[8 + s][lane] = make_float4(r7re.x, r7re.y, r7im.x, r7im.y);
    }
    __syncthreads();

    // round 8: nodes 1020, 1021
    if (s < 2) {
        float4 a = s_t[8 + 2 * s][lane], b = s_t[9 + 2 * s][lane];
        v2f r8re, r8im;
        node_cv((v2f){a.x, a.y}, (v2f){a.z, a.w}, (v2f){b.x, b.y}, (v2f){b.z, b.w},
                x2, &s_gate[6 * (1020 + s)], r8re, r8im);
        s_t[12 + s][lane] = make_float4(r8re.x, r8re.y, r8im.x, r8im.y);
    }
    __syncthreads();

    // round 9: node 1022 -> output
    if (s == 0) {
        float4 a = s_t[12][lane], b = s_t[13][lane];
        v2f r9re, r9im;
        node_cv((v2f){a.x, a.y}, (v2f){a.z, a.w}, (v2f){b.x, b.y}, (v2f){b.z, b.w},
                x2, &s_gate[6 * 1022], r9re, r9im);
        if (out_real_only) {
            out[e0]      = r9re.x;
            out[e0 + 64] = r9re.y;
        } else {
            reinterpret_cast<float2*>(out)[e0]      = make_float2(r9re.x, r9im.x);
            reinterpret_cast<float2*>(out)[e0 + 64] = make_float2(r9re.y, r9im.y);
        }
    }
}

extern "C" void kernel_launch(void* const* d_in, const int* in_sizes, int n_in,
                              void* d_out, int out_size, void* d_ws, size_t ws_size,
                              hipStream_t stream) {
    const float* x    = (const float*)d_in[0];
    const float* leaf = (const float*)d_in[1];
    const float* gate = (const float*)d_in[2];
    float* out = (float*)d_out;
    const int batch = in_sizes[0];

    const int out_real_only = (out_size == batch) ? 1 : 0;

    dim3 block(64, 8);
    dim3 grid(batch / 128);
    hipLaunchKernelGGL(EMLTree1DLinear_kernel, grid, block, 0, stream,
                       x, leaf, gate, out, batch, out_real_only);
}

// Round 4
// 140.632 us; speedup vs baseline: 2.5294x; 1.0091x over previous
//
#include <hip/hip_runtime.h>
#include <math.h>

#define CLAMPV 1000000.0f
#define PI_F     3.14159274f
#define HALFPI_F 1.57079633f
#define HALF_LN2 0.34657359f      // 0.5 * ln(2)
#define LN2_F    0.69314718f
#define L2E_F    1.44269504f      // 1/ln(2)
#define INV2PI_F 0.15915494f      // 1/(2*pi)

typedef float v2f __attribute__((ext_vector_type(2)));

__device__ __forceinline__ v2f vb(float s) { return (v2f){s, s}; }
__device__ __forceinline__ v2f vfma(v2f a, v2f b, v2f c) { return __builtin_elementwise_fma(a, b, c); }

// Wave-uniform gate pointer: readfirstlane forces the index into an SGPR so
// the 6 gate floats compile to s_load_* (scalar pipe, no VALU/LDS cost).
__device__ __forceinline__ const float* gptr(const float* __restrict__ g, int node) {
    return g + 6 * __builtin_amdgcn_readfirstlane(node);
}

// sanitize: nan -> 0, clamp to [-1e6,1e6] (med3 absorbs +-inf)
__device__ __forceinline__ v2f sanitv(v2f v) {
    v2f c;
    c.x = __builtin_amdgcn_fmed3f(v.x, -CLAMPV, CLAMPV);
    c.y = __builtin_amdgcn_fmed3f(v.y, -CLAMPV, CLAMPV);
    c.x = (v.x != v.x) ? 0.0f : c.x;
    c.y = (v.y != v.y) ? 0.0f : c.y;
    return c;
}

// packed fast atan2 (deg-11 minimax); (+0, x<0) -> +pi matches numpy for the
// exact-zero-imag chains (imag forced to +0 upstream).
__device__ __forceinline__ v2f fatan2v(v2f y, v2f x) {
    v2f ax = __builtin_elementwise_abs(x);
    v2f ay = __builtin_elementwise_abs(y);
    v2f mx = __builtin_elementwise_max(ax, ay);
    v2f mn = __builtin_elementwise_min(ax, ay);
    v2f r  = (v2f){__builtin_amdgcn_rcpf(mx.x), __builtin_amdgcn_rcpf(mx.y)};
    v2f t  = mn * r;
    v2f z  = t * t;
    v2f p  = vfma(z, vfma(z, vfma(z, vfma(z, vfma(z,
             vb(-0.0117212f), vb(0.05265332f)), vb(-0.11643287f)), vb(0.19354346f)),
             vb(-0.33262347f)), vb(0.99997726f));
    p = p * t;
    p.x = (ay.x > ax.x) ? (HALFPI_F - p.x) : p.x;
    p.y = (ay.y > ax.y) ? (HALFPI_F - p.y) : p.y;
    p.x = (x.x < 0.0f) ? (PI_F - p.x) : p.x;
    p.y = (x.y < 0.0f) ? (PI_F - p.y) : p.y;
    p.x = copysignf(p.x, y.x);
    p.y = copysignf(p.y, y.y);
    return p;
}

// exp(w) tail: out = sanitize(exp(wre) * (cos(wim) + i sin(wim)))
__device__ __forceinline__ void exp_tailv(v2f wre, v2f wim, v2f& ore, v2f& oim) {
    v2f e = wre * vb(L2E_F);
    v2f r = (v2f){__builtin_amdgcn_exp2f(e.x), __builtin_amdgcn_exp2f(e.y)};
    v2f f0 = wim * vb(INV2PI_F);
    v2f f = (v2f){__builtin_amdgcn_fractf(f0.x), __builtin_amdgcn_fractf(f0.y)};
    v2f sn = (v2f){__builtin_amdgcn_sinf(f.x), __builtin_amdgcn_sinf(f.y)};
    v2f cs = (v2f){__builtin_amdgcn_cosf(f.x), __builtin_amdgcn_cosf(f.y)};
    ore = sanitv(r * cs);
    oim = sanitv(r * sn);
}

// General node combine (complex children), 2 elements packed.
// fma(g2, lim, +0) forces -0 -> +0 on the imag parts (load-bearing for the
// atan2 branch choice when a child's imag is exactly zero).
__device__ __forceinline__ void node_cv(
    v2f lre, v2f lim, v2f rre, v2f rim,
    v2f x, const float* __restrict__ g,
    v2f& ore, v2f& oim)
{
    float g0 = g[0], g1 = g[1], g2 = g[2], g3 = g[3], g4 = g[4], g5 = g[5];
    v2f ure = vfma(vb(g2), lre, vfma(vb(g1), x, vb(g0)));
    v2f uim = vfma(vb(g2), lim, vb(0.0f));
    v2f vre = vfma(vb(g5), rre, vfma(vb(g4), x, vb(g3)));
    v2f vim = vfma(vb(g5), rim, vb(0.0f));

    v2f nu = vfma(ure, ure, uim * uim);
    v2f nv = vfma(vre, vre, vim * vim);
    v2f lure = vb(HALF_LN2) * (v2f){__builtin_amdgcn_logf(nu.x), __builtin_amdgcn_logf(nu.y)};
    v2f lvre = vb(HALF_LN2) * (v2f){__builtin_amdgcn_logf(nv.x), __builtin_amdgcn_logf(nv.y)};
    v2f luim = fatan2v(uim, ure);
    v2f lvim = fatan2v(vim, vre);

    v2f wre = vfma(lure, lvre, -(luim * lvim));
    v2f wim = vfma(lure, lvim, luim * lvre);
    exp_tailv(wre, wim, ore, oim);
}

// Round-0 node with real children (leaf values): no atan2 needed.
__device__ __forceinline__ void node_rv(
    v2f l, v2f r, v2f x, const float* __restrict__ g,
    v2f& ore, v2f& oim)
{
    float g0 = g[0], g1 = g[1], g2 = g[2], g3 = g[3], g4 = g[4], g5 = g[5];
    v2f u = vfma(vb(g2), l, vfma(vb(g1), x, vb(g0)));
    v2f v = vfma(vb(g5), r, vfma(vb(g4), x, vb(g3)));
    v2f au = __builtin_elementwise_abs(u);
    v2f av = __builtin_elementwise_abs(v);
    v2f lure = vb(LN2_F) * (v2f){__builtin_amdgcn_logf(au.x), __builtin_amdgcn_logf(au.y)};
    v2f lvre = vb(LN2_F) * (v2f){__builtin_amdgcn_logf(av.x), __builtin_amdgcn_logf(av.y)};
    v2f luim, lvim;
    luim.x = (u.x < 0.0f) ? PI_F : 0.0f;
    luim.y = (u.y < 0.0f) ? PI_F : 0.0f;
    lvim.x = (v.x < 0.0f) ? PI_F : 0.0f;
    lvim.y = (v.y < 0.0f) ? PI_F : 0.0f;

    v2f wre = vfma(lure, lvre, -(luim * lvim));
    v2f wim = vfma(lure, lvim, luim * lvre);
    exp_tailv(wre, wim, ore, oim);
}

// Block: 64 lanes x 8 subtrees (512 threads). Each lane owns 2 batch elements
// (e0 = blk*128 + lane, e1 = e0 + 64), all math 2-wide packed (v_pk_fma_f32).
// Gates + leaves are fetched via wave-uniform SCALAR loads (readfirstlane);
// LDS holds only the DFS stack (rounds 4-6) and the tail (rounds 7-9).
__global__ __launch_bounds__(512, 8) void EMLTree1DLinear_kernel(
    const float* __restrict__ x_g,      // [batch]
    const float* __restrict__ leaf_g,   // [1024][2]
    const float* __restrict__ gate_g,   // [1023][2][3] flat
    float* __restrict__ out,            // [batch][2] interleaved complex (or [batch] real)
    int batch, int out_real_only)
{
    __shared__ float4 s_stk[3][512];      // 24576 B  (re0,re1,im0,im1), rounds 3..5 pushes
    __shared__ float4 s_t[14][64];        // 14336 B  tail: 0..7 round-6, 8..11 round-7, 12..13 round-8

    const int lane = threadIdx.x;         // 0..63
    const int s    = threadIdx.y;         // subtree, 0..7
    const int tid  = lane + 64 * s;       // 0..511

    const int e0 = blockIdx.x * 128 + lane;
    const v2f x2 = (v2f){x_g[e0], x_g[e0 + 64]};

    v2f cre = vb(0.0f), cim = vb(0.0f);

    // 8 groups of 16 leaves
    for (int q = 0; q < 8; ++q) {
        const int jq = 128 * s + 16 * q;   // leftmost leaf of this group
        v2f r2re[2], r2im[2];
        v2f h1re = vb(0.0f), h1im = vb(0.0f);

#pragma unroll
        for (int p = 0; p < 4; ++p) {
            const int j = jq + 4 * p;
            // 4 leaves via scalar loads (wave-uniform address)
            const float* L = leaf_g + 2 * __builtin_amdgcn_readfirstlane(j);
            v2f l0 = vfma(vb(L[1]), x2, vb(L[0]));
            v2f l1 = vfma(vb(L[3]), x2, vb(L[2]));
            v2f l2 = vfma(vb(L[5]), x2, vb(L[4]));
            v2f l3 = vfma(vb(L[7]), x2, vb(L[6]));

            // round 0: nodes (j>>1), (j>>1)+1
            v2f Are, Aim, Bre, Bim;
            node_rv(l0, l1, x2, gptr(gate_g, j >> 1), Are, Aim);
            node_rv(l2, l3, x2, gptr(gate_g, (j >> 1) + 1), Bre, Bim);

            // round 1: node 512 + (j>>2)
            v2f r1re, r1im;
            node_cv(Are, Aim, Bre, Bim, x2, gptr(gate_g, 512 + (j >> 2)), r1re, r1im);

            if (p & 1) {
                // round 2: node 768 + (j>>3)
                node_cv(h1re, h1im, r1re, r1im, x2,
                        gptr(gate_g, 768 + (j >> 3)), r2re[p >> 1], r2im[p >> 1]);
            } else {
                h1re = r1re; h1im = r1im;
            }
        }
        // round 3: node 896 + (jq>>4)
        node_cv(r2re[0], r2im[0], r2re[1], r2im[1], x2,
                gptr(gate_g, 896 + (jq >> 4)), cre, cim);

        // rounds 4..6 via LDS stack (wave-uniform trip count)
        int idx = 8 * s + q;     // position at round 3
        int Rc = 3;
        while ((idx & 1) && (Rc < 6)) {
            const int node = (1024 - (1024 >> (Rc + 1))) + (idx >> 1);
            float4 st = s_stk[Rc - 3][tid];
            node_cv((v2f){st.x, st.y}, (v2f){st.z, st.w}, cre, cim,
                    x2, gptr(gate_g, node), cre, cim);
            idx >>= 1;
            ++Rc;
        }
        if (Rc < 6) s_stk[Rc - 3][tid] = make_float4(cre.x, cre.y, cim.x, cim.y);
    }

    // round-6 value (128-leaf subtree root) -> tail
    s_t[s][lane] = make_float4(cre.x, cre.y, cim.x, cim.y);
    __syncthreads();

    // round 7: nodes 1016..1019
    if (s < 4) {
        float4 a = s_t[2 * s][lane], b = s_t[2 * s + 1][lane];
        v2f r7re, r7im;
        node_cv((v2f){a.x, a.y}, (v2f){a.z, a.w}, (v2f){b.x, b.y}, (v2f){b.z, b.w},
                x2, gptr(gate_g, 1016 + s), r7re, r7im);
        s_t[8 + s][lane] = make_float4(r7re.x, r7re.y, r7im.x, r7im.y);
    }
    __syncthreads();

    // round 8: nodes 1020, 1021
    if (s < 2) {
        float4 a = s_t[8 + 2 * s][lane], b = s_t[9 + 2 * s][lane];
        v2f r8re, r8im;
        node_cv((v2f){a.x, a.y}, (v2f){a.z, a.w}, (v2f){b.x, b.y}, (v2f){b.z, b.w},
                x2, gptr(gate_g, 1020 + s), r8re, r8im);
        s_t[12 + s][lane] = make_float4(r8re.x, r8re.y, r8im.x, r8im.y);
    }
    __syncthreads();

    // round 9: node 1022 -> output
    if (s == 0) {
        float4 a = s_t[12][lane], b = s_t[13][lane];
        v2f r9re, r9im;
        node_cv((v2f){a.x, a.y}, (v2f){a.z, a.w}, (v2f){b.x, b.y}, (v2f){b.z, b.w},
                x2, gptr(gate_g, 1022), r9re, r9im);
        if (out_real_only) {
            out[e0]      = r9re.x;
            out[e0 + 64] = r9re.y;
        } else {
            reinterpret_cast<float2*>(out)[e0]      = make_float2(r9re.x, r9im.x);
            reinterpret_cast<float2*>(out)[e0 + 64] = make_float2(r9re.y, r9im.y);
        }
    }
}

extern "C" void kernel_launch(void* const* d_in, const int* in_sizes, int n_in,
                              void* d_out, int out_size, void* d_ws, size_t ws_size,
                              hipStream_t stream) {
    const float* x    = (const float*)d_in[0];
    const float* leaf = (const float*)d_in[1];
    const float* gate = (const float*)d_in[2];
    float* out = (float*)d_out;
    const int batch = in_sizes[0];

    const int out_real_only = (out_size == batch) ? 1 : 0;

    dim3 block(64, 8);
    dim3 grid(batch / 128);
    hipLaunchKernelGGL(EMLTree1DLinear_kernel, grid, block, 0, stream,
                       x, leaf, gate, out, batch, out_real_only);
}

// Round 5
// 138.073 us; speedup vs baseline: 2.5763x; 1.0185x over previous
//
#include <hip/hip_runtime.h>
#include <math.h>

#define CLAMPV 1000000.0f
#define PI_F     3.14159274f
#define HALFPI_F 1.57079633f
#define HALF_LN2 0.34657359f      // 0.5 * ln(2)
#define LN2_F    0.69314718f
#define L2E_F    1.44269504f      // 1/ln(2)
#define INV2PI_F 0.15915494f      // 1/(2*pi)

typedef float v2f __attribute__((ext_vector_type(2)));

__device__ __forceinline__ v2f vb(float s) { return (v2f){s, s}; }
__device__ __forceinline__ v2f vfma(v2f a, v2f b, v2f c) { return __builtin_elementwise_fma(a, b, c); }

// Wave-uniform gate pointer: readfirstlane forces the index into an SGPR so
// the 6 gate floats compile to s_load_* (scalar pipe, no VALU/LDS cost).
__device__ __forceinline__ const float* gptr(const float* __restrict__ g, int node) {
    return g + 6 * __builtin_amdgcn_readfirstlane(node);
}

// sanitize: nan -> 0, clamp to [-1e6,1e6] (med3 absorbs +-inf)
__device__ __forceinline__ v2f sanitv(v2f v) {
    v2f c;
    c.x = __builtin_amdgcn_fmed3f(v.x, -CLAMPV, CLAMPV);
    c.y = __builtin_amdgcn_fmed3f(v.y, -CLAMPV, CLAMPV);
    c.x = (v.x != v.x) ? 0.0f : c.x;
    c.y = (v.y != v.y) ? 0.0f : c.y;
    return c;
}

// packed fast atan2 (deg-11 minimax); (+0, x<0) -> +pi matches numpy for the
// exact-zero-imag chains (imag forced to +0 upstream).
__device__ __forceinline__ v2f fatan2v(v2f y, v2f x) {
    v2f ax = __builtin_elementwise_abs(x);
    v2f ay = __builtin_elementwise_abs(y);
    v2f mx = __builtin_elementwise_max(ax, ay);
    v2f mn = __builtin_elementwise_min(ax, ay);
    v2f r  = (v2f){__builtin_amdgcn_rcpf(mx.x), __builtin_amdgcn_rcpf(mx.y)};
    v2f t  = mn * r;
    v2f z  = t * t;
    v2f p  = vfma(z, vfma(z, vfma(z, vfma(z, vfma(z,
             vb(-0.0117212f), vb(0.05265332f)), vb(-0.11643287f)), vb(0.19354346f)),
             vb(-0.33262347f)), vb(0.99997726f));
    p = p * t;
    p.x = (ay.x > ax.x) ? (HALFPI_F - p.x) : p.x;
    p.y = (ay.y > ax.y) ? (HALFPI_F - p.y) : p.y;
    p.x = (x.x < 0.0f) ? (PI_F - p.x) : p.x;
    p.y = (x.y < 0.0f) ? (PI_F - p.y) : p.y;
    p.x = copysignf(p.x, y.x);
    p.y = copysignf(p.y, y.y);
    return p;
}

// exp(w) tail: out = sanitize(exp(wre) * (cos(wim) + i sin(wim)))
__device__ __forceinline__ void exp_tailv(v2f wre, v2f wim, v2f& ore, v2f& oim) {
    v2f e = wre * vb(L2E_F);
    v2f r = (v2f){__builtin_amdgcn_exp2f(e.x), __builtin_amdgcn_exp2f(e.y)};
    v2f f0 = wim * vb(INV2PI_F);
    v2f f = (v2f){__builtin_amdgcn_fractf(f0.x), __builtin_amdgcn_fractf(f0.y)};
    v2f sn = (v2f){__builtin_amdgcn_sinf(f.x), __builtin_amdgcn_sinf(f.y)};
    v2f cs = (v2f){__builtin_amdgcn_cosf(f.x), __builtin_amdgcn_cosf(f.y)};
    ore = sanitv(r * cs);
    oim = sanitv(r * sn);
}

// General node combine (complex children), 2 elements packed.
// fma(g2, lim, +0) forces -0 -> +0 on the imag parts (load-bearing for the
// atan2 branch choice when a child's imag is exactly zero).
__device__ __forceinline__ void node_cv(
    v2f lre, v2f lim, v2f rre, v2f rim,
    v2f x, const float* __restrict__ g,
    v2f& ore, v2f& oim)
{
    float g0 = g[0], g1 = g[1], g2 = g[2], g3 = g[3], g4 = g[4], g5 = g[5];
    v2f ure = vfma(vb(g2), lre, vfma(vb(g1), x, vb(g0)));
    v2f uim = vfma(vb(g2), lim, vb(0.0f));
    v2f vre = vfma(vb(g5), rre, vfma(vb(g4), x, vb(g3)));
    v2f vim = vfma(vb(g5), rim, vb(0.0f));

    v2f nu = vfma(ure, ure, uim * uim);
    v2f nv = vfma(vre, vre, vim * vim);
    v2f lure = vb(HALF_LN2) * (v2f){__builtin_amdgcn_logf(nu.x), __builtin_amdgcn_logf(nu.y)};
    v2f lvre = vb(HALF_LN2) * (v2f){__builtin_amdgcn_logf(nv.x), __builtin_amdgcn_logf(nv.y)};
    v2f luim = fatan2v(uim, ure);
    v2f lvim = fatan2v(vim, vre);

    v2f wre = vfma(lure, lvre, -(luim * lvim));
    v2f wim = vfma(lure, lvim, luim * lvre);
    exp_tailv(wre, wim, ore, oim);
}

// Round-0 node with real children (leaf values): no atan2 needed.
__device__ __forceinline__ void node_rv(
    v2f l, v2f r, v2f x, const float* __restrict__ g,
    v2f& ore, v2f& oim)
{
    float g0 = g[0], g1 = g[1], g2 = g[2], g3 = g[3], g4 = g[4], g5 = g[5];
    v2f u = vfma(vb(g2), l, vfma(vb(g1), x, vb(g0)));
    v2f v = vfma(vb(g5), r, vfma(vb(g4), x, vb(g3)));
    v2f au = __builtin_elementwise_abs(u);
    v2f av = __builtin_elementwise_abs(v);
    v2f lure = vb(LN2_F) * (v2f){__builtin_amdgcn_logf(au.x), __builtin_amdgcn_logf(au.y)};
    v2f lvre = vb(LN2_F) * (v2f){__builtin_amdgcn_logf(av.x), __builtin_amdgcn_logf(av.y)};
    v2f luim, lvim;
    luim.x = (u.x < 0.0f) ? PI_F : 0.0f;
    luim.y = (u.y < 0.0f) ? PI_F : 0.0f;
    lvim.x = (v.x < 0.0f) ? PI_F : 0.0f;
    lvim.y = (v.y < 0.0f) ? PI_F : 0.0f;

    v2f wre = vfma(lure, lvre, -(luim * lvim));
    v2f wim = vfma(lure, lvim, luim * lvre);
    exp_tailv(wre, wim, ore, oim);
}

// Block: 64 lanes x 16 subtrees (1024 threads = 16 waves). Each lane owns 2
// batch elements (e0 = blk*128 + lane, e1 = e0 + 64), math 2-wide packed.
// Each thread reduces a 64-leaf subtree: rounds 0-3 in registers (4 groups of
// 16 leaves), rounds 4-5 via 2-level LDS stack, rounds 6-9 in the LDS tail.
// Grid 512 x 16 waves = 8192 waves = 32 waves/CU (fills the device).
__global__ __launch_bounds__(1024, 8) void EMLTree1DLinear_kernel(
    const float* __restrict__ x_g,      // [batch]
    const float* __restrict__ leaf_g,   // [1024][2]
    const float* __restrict__ gate_g,   // [1023][2][3] flat
    float* __restrict__ out,            // [batch][2] interleaved complex (or [batch] real)
    int batch, int out_real_only)
{
    __shared__ float4 s_stk[2][1024];     // 32768 B  (re0,re1,im0,im1), round-3/4 pushes
    __shared__ float4 s_t[30][64];        // 30720 B  tail: 0..15 round-5 roots,
                                          //          16..23 r6, 24..27 r7, 28..29 r8
    const int lane = threadIdx.x;         // 0..63
    const int s    = threadIdx.y;         // subtree, 0..15
    const int tid  = lane + 64 * s;       // 0..1023

    const int e0 = blockIdx.x * 128 + lane;
    const v2f x2 = (v2f){x_g[e0], x_g[e0 + 64]};

    v2f cre = vb(0.0f), cim = vb(0.0f);

    // 4 groups of 16 leaves (64-leaf subtree per thread)
    for (int q = 0; q < 4; ++q) {
        const int jq = 64 * s + 16 * q;    // leftmost leaf of this group
        v2f r2re[2], r2im[2];
        v2f h1re = vb(0.0f), h1im = vb(0.0f);

#pragma unroll
        for (int p = 0; p < 4; ++p) {
            const int j = jq + 4 * p;
            // 4 leaves via scalar loads (wave-uniform address)
            const float* L = leaf_g + 2 * __builtin_amdgcn_readfirstlane(j);
            v2f l0 = vfma(vb(L[1]), x2, vb(L[0]));
            v2f l1 = vfma(vb(L[3]), x2, vb(L[2]));
            v2f l2 = vfma(vb(L[5]), x2, vb(L[4]));
            v2f l3 = vfma(vb(L[7]), x2, vb(L[6]));

            // round 0: nodes (j>>1), (j>>1)+1
            v2f Are, Aim, Bre, Bim;
            node_rv(l0, l1, x2, gptr(gate_g, j >> 1), Are, Aim);
            node_rv(l2, l3, x2, gptr(gate_g, (j >> 1) + 1), Bre, Bim);

            // round 1: node 512 + (j>>2)
            v2f r1re, r1im;
            node_cv(Are, Aim, Bre, Bim, x2, gptr(gate_g, 512 + (j >> 2)), r1re, r1im);

            if (p & 1) {
                // round 2: node 768 + (j>>3)
                node_cv(h1re, h1im, r1re, r1im, x2,
                        gptr(gate_g, 768 + (j >> 3)), r2re[p >> 1], r2im[p >> 1]);
            } else {
                h1re = r1re; h1im = r1im;
            }
        }
        // round 3: node 896 + (jq>>4)
        node_cv(r2re[0], r2im[0], r2re[1], r2im[1], x2,
                gptr(gate_g, 896 + (jq >> 4)), cre, cim);

        // rounds 4..5 via 2-level LDS stack (wave-uniform trip count).
        // idx = position at round 3 = 4*s + q; stop before crossing the
        // per-thread subtree root (round 5).
        int idx = 4 * s + q;
        int Rc = 3;
        while ((idx & 1) && (Rc < 5)) {
            const int node = (1024 - (1024 >> (Rc + 1))) + (idx >> 1);
            float4 st = s_stk[Rc - 3][tid];
            node_cv((v2f){st.x, st.y}, (v2f){st.z, st.w}, cre, cim,
                    x2, gptr(gate_g, node), cre, cim);
            idx >>= 1;
            ++Rc;
        }
        if (Rc < 5) s_stk[Rc - 3][tid] = make_float4(cre.x, cre.y, cim.x, cim.y);
    }

    // round-5 value (64-leaf subtree root, position s) -> tail
    s_t[s][lane] = make_float4(cre.x, cre.y, cim.x, cim.y);
    __syncthreads();

    // round 6: nodes 1008..1015 (8 positions)
    if (s < 8) {
        float4 a = s_t[2 * s][lane], b = s_t[2 * s + 1][lane];
        v2f rre, rim;
        node_cv((v2f){a.x, a.y}, (v2f){a.z, a.w}, (v2f){b.x, b.y}, (v2f){b.z, b.w},
                x2, gptr(gate_g, 1008 + s), rre, rim);
        s_t[16 + s][lane] = make_float4(rre.x, rre.y, rim.x, rim.y);
    }
    __syncthreads();

    // round 7: nodes 1016..1019
    if (s < 4) {
        float4 a = s_t[16 + 2 * s][lane], b = s_t[17 + 2 * s][lane];
        v2f rre, rim;
        node_cv((v2f){a.x, a.y}, (v2f){a.z, a.w}, (v2f){b.x, b.y}, (v2f){b.z, b.w},
                x2, gptr(gate_g, 1016 + s), rre, rim);
        s_t[24 + s][lane] = make_float4(rre.x, rre.y, rim.x, rim.y);
    }
    __syncthreads();

    // round 8: nodes 1020, 1021
    if (s < 2) {
        float4 a = s_t[24 + 2 * s][lane], b = s_t[25 + 2 * s][lane];
        v2f rre, rim;
        node_cv((v2f){a.x, a.y}, (v2f){a.z, a.w}, (v2f){b.x, b.y}, (v2f){b.z, b.w},
                x2, gptr(gate_g, 1020 + s), rre, rim);
        s_t[28 + s][lane] = make_float4(rre.x, rre.y, rim.x, rim.y);
    }
    __syncthreads();

    // round 9: node 1022 -> output
    if (s == 0) {
        float4 a = s_t[28][lane], b = s_t[29][lane];
        v2f rre, rim;
        node_cv((v2f){a.x, a.y}, (v2f){a.z, a.w}, (v2f){b.x, b.y}, (v2f){b.z, b.w},
                x2, gptr(gate_g, 1022), rre, rim);
        if (out_real_only) {
            out[e0]      = rre.x;
            out[e0 + 64] = rre.y;
        } else {
            reinterpret_cast<float2*>(out)[e0]      = make_float2(rre.x, rim.x);
            reinterpret_cast<float2*>(out)[e0 + 64] = make_float2(rre.y, rim.y);
        }
    }
}

extern "C" void kernel_launch(void* const* d_in, const int* in_sizes, int n_in,
                              void* d_out, int out_size, void* d_ws, size_t ws_size,
                              hipStream_t stream) {
    const float* x    = (const float*)d_in[0];
    const float* leaf = (const float*)d_in[1];
    const float* gate = (const float*)d_in[2];
    float* out = (float*)d_out;
    const int batch = in_sizes[0];

    const int out_real_only = (out_size == batch) ? 1 : 0;

    dim3 block(64, 16);
    dim3 grid(batch / 128);
    hipLaunchKernelGGL(EMLTree1DLinear_kernel, grid, block, 0, stream,
                       x, leaf, gate, out, batch, out_real_only);
}